// Round 5
// baseline (970.296 us; speedup 1.0000x reference)
//
#include <hip/hip_runtime.h>
#include <hip/hip_fp16.h>

constexpr int N  = 50000;
constexpr int E  = 1600000;
constexpr int T  = 8;
constexpr int H  = 64;
constexpr int C  = 10;

// ---------------- degree + histogram ----------------
__global__ void deg_count_kernel(const int* __restrict__ ei, const float* __restrict__ w,
                                 float* __restrict__ deg, int* __restrict__ counts) {
  int e = blockIdx.x * blockDim.x + threadIdx.x;
  if (e >= E) return;
  int d = ei[E + e];
  atomicAdd(&deg[d], w[e]);
  atomicAdd(&counts[d], 1);
}

__global__ void dinv_kernel(float* deg) {
  int n = blockIdx.x * blockDim.x + threadIdx.x;
  if (n >= N) return;
  deg[n] = rsqrtf(deg[n] + 1.0f);  // +1 = self-loop weight
}

// ---------------- exclusive scan (single block, 1024 threads) ----------------
__global__ void scan_kernel(const int* __restrict__ counts, int* __restrict__ rowptr) {
  __shared__ int wsum[16];
  __shared__ int carry_s;
  int tid = threadIdx.x;
  if (tid == 0) carry_s = 0;
  __syncthreads();
  for (int base = 0; base < N; base += 1024) {
    int i = base + tid;
    int v = (i < N) ? counts[i] : 0;
    int x = v;
    #pragma unroll
    for (int off = 1; off < 64; off <<= 1) {
      int y = __shfl_up(x, off, 64);
      if ((tid & 63) >= off) x += y;
    }
    if ((tid & 63) == 63) wsum[tid >> 6] = x;
    __syncthreads();
    if (tid < 16) {
      int wv = wsum[tid];
      #pragma unroll
      for (int off = 1; off < 16; off <<= 1) {
        int y = __shfl_up(wv, off, 16);
        if (tid >= off) wv += y;
      }
      wsum[tid] = wv;
    }
    __syncthreads();
    int carry = carry_s;
    int waveoff = (tid >> 6) ? wsum[(tid >> 6) - 1] : 0;
    int inc = x + waveoff + carry;
    if (i < N) rowptr[i + 1] = inc;
    __syncthreads();
    if (tid == 1023) carry_s = inc;
    __syncthreads();
  }
  if (tid == 0) rowptr[0] = 0;
}

// ---------------- CSR fill ----------------
__global__ void fill_kernel(const int* __restrict__ ei, const float* __restrict__ w,
                            const float* __restrict__ dinv, const int* __restrict__ rowptr,
                            int* __restrict__ fill, int* __restrict__ csr_src,
                            float* __restrict__ csr_norm) {
  int e = blockIdx.x * blockDim.x + threadIdx.x;
  if (e >= E) return;
  int s = ei[e], d = ei[E + e];
  int pos = rowptr[d] + atomicAdd(&fill[d], 1);
  csr_src[pos] = s;
  csr_norm[pos] = dinv[s] * w[e] * dinv[d];
}

// ---------------- sort each CSR row by src id (bitonic, 1 wave/node, cap 128) ----------------
__global__ void sort_rows_kernel(const int* __restrict__ rowptr, int* __restrict__ csr_src,
                                 float* __restrict__ csr_nrm) {
  __shared__ int   ks[4][128];
  __shared__ float vs[4][128];
  int tid = threadIdx.x;
  int w = tid >> 6, l = tid & 63;
  int n = blockIdx.x * 4 + w;
  int e0 = rowptr[n], e1 = rowptr[n + 1];
  int cnt = e1 - e0; if (cnt > 128) cnt = 128;   // Poisson(32): P(deg>128) ~ 0
  #pragma unroll
  for (int i = l; i < 128; i += 64) {
    if (i < cnt) { ks[w][i] = csr_src[e0 + i]; vs[w][i] = csr_nrm[e0 + i]; }
    else         { ks[w][i] = 0x7fffffff;      vs[w][i] = 0.f; }
  }
  __syncthreads();
  for (int k = 2; k <= 128; k <<= 1) {
    for (int j = k >> 1; j > 0; j >>= 1) {
      #pragma unroll
      for (int i = l; i < 128; i += 64) {
        int partner = i ^ j;
        if (partner > i) {
          bool up = ((i & k) == 0);
          int ka = ks[w][i], kb = ks[w][partner];
          if ((ka > kb) == up) {
            float va = vs[w][i], vb = vs[w][partner];
            ks[w][i] = kb; ks[w][partner] = ka;
            vs[w][i] = vb; vs[w][partner] = va;
          }
        }
      }
      __syncthreads();
    }
  }
  #pragma unroll
  for (int i = l; i < 128; i += 64) {
    if (i < cnt) { csr_src[e0 + i] = ks[w][i]; csr_nrm[e0 + i] = vs[w][i]; }
  }
}

// ---------------- x (fp32) -> xh (fp16) ----------------
__global__ void cvt_x_kernel(const float* __restrict__ x, __half* __restrict__ xh) {
  int i = blockIdx.x * blockDim.x + threadIdx.x;  // over N*32 float4s
  if (i >= N * 32) return;
  float4 v = ((const float4*)x)[i];
  __half2 h0; h0.x = __float2half_rn(v.x); h0.y = __float2half_rn(v.y);
  __half2 h1; h1.x = __float2half_rn(v.z); h1.y = __float2half_rn(v.w);
  uint2 u;
  u.x = __builtin_bit_cast(unsigned int, h0);
  u.y = __builtin_bit_cast(unsigned int, h1);
  ((uint2*)xh)[i] = u;
}

// ---------------- xagg = Ahat @ X, fp16 rows (256B), wave/node ----------------
__global__ void agg_x_kernel(const __half* __restrict__ xh, const float* __restrict__ dinv,
                             const int* __restrict__ rowptr, const int* __restrict__ csr_src,
                             const float* __restrict__ csr_norm, float* __restrict__ xagg) {
  int tid = threadIdx.x;
  int w = tid >> 6, l = tid & 63;
  int sub = l >> 5, c4 = l & 31;     // half-wave: 2 items x 32 lanes x 4ch
  int n = blockIdx.x * 4 + w;
  float di = dinv[n], dd = di * di;
  int e0 = rowptr[n], e1 = rowptr[n + 1];
  int cnt = e1 - e0 + 1;             // item 0 = self
  float4 acc = {0, 0, 0, 0};
  int sm[2]; float wm[2];
  #pragma unroll
  for (int q = 0; q < 2; ++q) {
    int idx = sub + 2 * q;
    if (idx == 0)       { sm[q] = n; wm[q] = dd; }
    else if (idx < cnt) { int e = e0 + idx - 1; sm[q] = csr_src[e]; wm[q] = csr_norm[e]; }
    else                { sm[q] = n; wm[q] = 0.f; }
  }
  for (int i = sub; i < cnt; i += 4) {
    uint2 r0 = *reinterpret_cast<const uint2*>(xh + (size_t)sm[0] * 128 + c4 * 4);
    uint2 r1 = *reinterpret_cast<const uint2*>(xh + (size_t)sm[1] * 128 + c4 * 4);
    float w0 = wm[0], w1 = wm[1];
    #pragma unroll
    for (int q = 0; q < 2; ++q) {
      int idx = i + 4 + 2 * q;
      if (idx < cnt) { int e = e0 + idx - 1; sm[q] = csr_src[e]; wm[q] = csr_norm[e]; }
      else           { sm[q] = n; wm[q] = 0.f; }
    }
    float2 f0 = __half22float2(__builtin_bit_cast(__half2, r0.x));
    float2 f1 = __half22float2(__builtin_bit_cast(__half2, r0.y));
    acc.x = fmaf(w0, f0.x, acc.x); acc.y = fmaf(w0, f0.y, acc.y);
    acc.z = fmaf(w0, f1.x, acc.z); acc.w = fmaf(w0, f1.y, acc.w);
    float2 g0 = __half22float2(__builtin_bit_cast(__half2, r1.x));
    float2 g1 = __half22float2(__builtin_bit_cast(__half2, r1.y));
    acc.x = fmaf(w1, g0.x, acc.x); acc.y = fmaf(w1, g0.y, acc.y);
    acc.z = fmaf(w1, g1.x, acc.z); acc.w = fmaf(w1, g1.y, acc.w);
  }
  acc.x += __shfl_xor(acc.x, 32, 64);
  acc.y += __shfl_xor(acc.y, 32, 64);
  acc.z += __shfl_xor(acc.z, 32, 64);
  acc.w += __shfl_xor(acc.w, 32, 64);
  if (sub == 0) ((float4*)(xagg + (size_t)n * 128))[c4] = acc;
}

// ---------------- dense: h1 = relu(xagg_t @ W1 + b1); G2 = h1 @ W2 (fp16, all t) ----------------
__global__ void dense12_kernel(const float* __restrict__ xagg, const float* __restrict__ W1,
                               const float* __restrict__ b1, const float* __restrict__ W2,
                               __half* __restrict__ G2h) {
  __shared__ float xs[4 * 128];
  __shared__ float h1s[4][8][64];
  int tid = threadIdx.x;
  int n0 = blockIdx.x * 4;
  ((float2*)xs)[tid] = ((const float2*)(xagg + (size_t)n0 * 128))[tid];
  __syncthreads();
  int nb = tid >> 6, j = tid & 63;
  float a[8];
  float bj = b1[j];
  #pragma unroll
  for (int t = 0; t < 8; ++t) a[t] = bj;
  for (int f = 0; f < 16; ++f) {
    float wv = W1[f * 64 + j];
    #pragma unroll
    for (int t = 0; t < 8; ++t) a[t] = fmaf(xs[nb * 128 + f * 8 + t], wv, a[t]);
  }
  #pragma unroll
  for (int t = 0; t < 8; ++t) h1s[nb][t][j] = fmaxf(a[t], 0.f);
  __syncthreads();
  float g[8];
  #pragma unroll
  for (int t = 0; t < 8; ++t) g[t] = 0.f;
  for (int k = 0; k < 64; ++k) {
    float wv = W2[k * 64 + j];
    #pragma unroll
    for (int t = 0; t < 8; ++t) g[t] = fmaf(h1s[nb][t][k], wv, g[t]);
  }
  __half* gp = G2h + (size_t)(n0 + nb) * 512 + j;
  #pragma unroll
  for (int t = 0; t < 8; ++t) gp[t * 64] = __float2half_rn(g[t]);
}

// 8-halves fused accumulate helper
__device__ __forceinline__ void accum8(float* acc, uint4 r, float wgt) {
  float2 f0 = __half22float2(__builtin_bit_cast(__half2, r.x));
  float2 f1 = __half22float2(__builtin_bit_cast(__half2, r.y));
  float2 f2 = __half22float2(__builtin_bit_cast(__half2, r.z));
  float2 f3 = __half22float2(__builtin_bit_cast(__half2, r.w));
  acc[0] = fmaf(wgt, f0.x, acc[0]); acc[1] = fmaf(wgt, f0.y, acc[1]);
  acc[2] = fmaf(wgt, f1.x, acc[2]); acc[3] = fmaf(wgt, f1.y, acc[3]);
  acc[4] = fmaf(wgt, f2.x, acc[4]); acc[5] = fmaf(wgt, f2.y, acc[5]);
  acc[6] = fmaf(wgt, f3.x, acc[6]); acc[7] = fmaf(wgt, f3.y, acc[7]);
}

// ---------------- conv2: aggregate G2h (1KB fp16 rows, 4-deep pipeline); h2=relu(+b2); G3h = h2 @ W3 ----------------
__global__ void conv2w_kernel(const __half* __restrict__ G2h, const float* __restrict__ dinv,
                              const int* __restrict__ rowptr, const int* __restrict__ csr_src,
                              const float* __restrict__ csr_norm, const float* __restrict__ b2,
                              const float* __restrict__ W3, __half* __restrict__ G3h) {
  __shared__ float h2s[4][512];
  int tid = threadIdx.x;
  int w = tid >> 6, l = tid & 63;
  int n0 = blockIdx.x * 4;
  int n = n0 + w;
  float di = dinv[n], dd = di * di;
  int e0 = rowptr[n], e1 = rowptr[n + 1];
  int cnt = e1 - e0 + 1;             // item 0 = self
  float acc[8] = {0, 0, 0, 0, 0, 0, 0, 0};
  int sm[4]; float wm[4];
  #pragma unroll
  for (int q = 0; q < 4; ++q) {
    int idx = q;
    if (idx == 0)       { sm[q] = n; wm[q] = dd; }
    else if (idx < cnt) { int e = e0 + idx - 1; sm[q] = csr_src[e]; wm[q] = csr_norm[e]; }
    else                { sm[q] = n; wm[q] = 0.f; }
  }
  for (int i = 0; i < cnt; i += 4) {
    uint4 r0 = *reinterpret_cast<const uint4*>(G2h + (size_t)sm[0] * 512 + l * 8);
    uint4 r1 = *reinterpret_cast<const uint4*>(G2h + (size_t)sm[1] * 512 + l * 8);
    uint4 r2 = *reinterpret_cast<const uint4*>(G2h + (size_t)sm[2] * 512 + l * 8);
    uint4 r3 = *reinterpret_cast<const uint4*>(G2h + (size_t)sm[3] * 512 + l * 8);
    float w0 = wm[0], w1 = wm[1], w2 = wm[2], w3 = wm[3];
    #pragma unroll
    for (int q = 0; q < 4; ++q) {
      int idx = i + 4 + q;           // >= 4, never self
      if (idx < cnt) { int e = e0 + idx - 1; sm[q] = csr_src[e]; wm[q] = csr_norm[e]; }
      else           { sm[q] = n; wm[q] = 0.f; }
    }
    accum8(acc, r0, w0);
    accum8(acc, r1, w1);
    accum8(acc, r2, w2);
    accum8(acc, r3, w3);
  }
  #pragma unroll
  for (int q = 0; q < 8; ++q)
    h2s[w][l * 8 + q] = fmaxf(acc[q] + b2[(l * 8 + q) & 63], 0.f);
  __syncthreads();
  // per-t dense: G3[t*64 + j] = sum_k h2[t*64+k] * W3[k][j]
  int t = tid >> 5;            // 0..7
  int jh = tid & 31, j0 = 2 * jh;
  float g[4][2];
  #pragma unroll
  for (int q = 0; q < 4; ++q) { g[q][0] = 0.f; g[q][1] = 0.f; }
  const float2* W3v = (const float2*)W3;
  for (int k = 0; k < 64; ++k) {
    float2 wv = W3v[k * 32 + jh];
    #pragma unroll
    for (int q = 0; q < 4; ++q) {
      float h = h2s[q][t * 64 + k];
      g[q][0] = fmaf(h, wv.x, g[q][0]);
      g[q][1] = fmaf(h, wv.y, g[q][1]);
    }
  }
  #pragma unroll
  for (int q = 0; q < 4; ++q) {
    __half2 hv;
    hv.x = __float2half_rn(g[q][0]);
    hv.y = __float2half_rn(g[q][1]);
    *reinterpret_cast<__half2*>(G3h + (size_t)(n0 + q) * 512 + t * 64 + j0) = hv;
  }
}

// ---------------- conv3 + head: aggregate G3h (4-deep); h3=relu(+b3); out = relu(h3@Wseq+bseq)@Wcls+bcls ----------------
__global__ void conv3w_kernel(const __half* __restrict__ G3h, const float* __restrict__ dinv,
                              const int* __restrict__ rowptr, const int* __restrict__ csr_src,
                              const float* __restrict__ csr_norm, const float* __restrict__ b3,
                              const float* __restrict__ Wseq, const float* __restrict__ bseq,
                              const float* __restrict__ Wcls, const float* __restrict__ bcls,
                              float* __restrict__ out) {
  __shared__ float h3s[4][512];
  __shared__ float red[4][4][64];
  __shared__ float hfs[4][64];
  int tid = threadIdx.x;
  int w = tid >> 6, l = tid & 63;
  int n0 = blockIdx.x * 4;
  int n = n0 + w;
  float di = dinv[n], dd = di * di;
  int e0 = rowptr[n], e1 = rowptr[n + 1];
  int cnt = e1 - e0 + 1;
  float acc[8] = {0, 0, 0, 0, 0, 0, 0, 0};
  int sm[4]; float wm[4];
  #pragma unroll
  for (int q = 0; q < 4; ++q) {
    int idx = q;
    if (idx == 0)       { sm[q] = n; wm[q] = dd; }
    else if (idx < cnt) { int e = e0 + idx - 1; sm[q] = csr_src[e]; wm[q] = csr_norm[e]; }
    else                { sm[q] = n; wm[q] = 0.f; }
  }
  for (int i = 0; i < cnt; i += 4) {
    uint4 r0 = *reinterpret_cast<const uint4*>(G3h + (size_t)sm[0] * 512 + l * 8);
    uint4 r1 = *reinterpret_cast<const uint4*>(G3h + (size_t)sm[1] * 512 + l * 8);
    uint4 r2 = *reinterpret_cast<const uint4*>(G3h + (size_t)sm[2] * 512 + l * 8);
    uint4 r3 = *reinterpret_cast<const uint4*>(G3h + (size_t)sm[3] * 512 + l * 8);
    float w0 = wm[0], w1 = wm[1], w2 = wm[2], w3 = wm[3];
    #pragma unroll
    for (int q = 0; q < 4; ++q) {
      int idx = i + 4 + q;
      if (idx < cnt) { int e = e0 + idx - 1; sm[q] = csr_src[e]; wm[q] = csr_norm[e]; }
      else           { sm[q] = n; wm[q] = 0.f; }
    }
    accum8(acc, r0, w0);
    accum8(acc, r1, w1);
    accum8(acc, r2, w2);
    accum8(acc, r3, w3);
  }
  #pragma unroll
  for (int q = 0; q < 8; ++q)
    h3s[w][l * 8 + q] = fmaxf(acc[q] + b3[(l * 8 + q) & 63], 0.f);
  __syncthreads();
  // seq contraction: partial[p][nb][j] = sum_{c in p-range} h3[nb][c] * Wseq[c][j]
  int p = tid >> 6, j = tid & 63;
  float pa0 = 0.f, pa1 = 0.f, pa2 = 0.f, pa3 = 0.f;
  for (int ci = 0; ci < 128; ++ci) {
    int c = p * 128 + ci;
    float wv = Wseq[(size_t)c * 64 + j];
    pa0 = fmaf(h3s[0][c], wv, pa0);
    pa1 = fmaf(h3s[1][c], wv, pa1);
    pa2 = fmaf(h3s[2][c], wv, pa2);
    pa3 = fmaf(h3s[3][c], wv, pa3);
  }
  red[p][0][j] = pa0; red[p][1][j] = pa1; red[p][2][j] = pa2; red[p][3][j] = pa3;
  __syncthreads();
  int nb = tid >> 6, k = tid & 63;
  float s = red[0][nb][k] + red[1][nb][k] + red[2][nb][k] + red[3][nb][k] + bseq[k];
  hfs[nb][k] = fmaxf(s, 0.f);
  __syncthreads();
  if (k < C) {
    float o = bcls[k];
    #pragma unroll
    for (int kk = 0; kk < 64; ++kk) o = fmaf(hfs[nb][kk], Wcls[kk * C + k], o);
    out[(size_t)(n0 + nb) * C + k] = o;
  }
}

// ================= NARROW FALLBACK (fp32, per-t) =================
__global__ void layer1N_kernel(const float* __restrict__ xagg, const float* __restrict__ W1,
                               const float* __restrict__ b1, const float* __restrict__ W2,
                               float* __restrict__ GA, int t) {
  __shared__ float hs[4][H];
  int tid = threadIdx.x;
  int wv = tid >> 6, j = tid & 63;
  int n = blockIdx.x * 4 + wv;
  const float* xa = xagg + (size_t)n * 128;
  float a = b1[j];
  #pragma unroll
  for (int f = 0; f < 16; ++f) a += xa[f * 8 + t] * W1[f * H + j];
  hs[wv][j] = fmaxf(a, 0.f);
  __syncthreads();
  float g = 0.f;
  #pragma unroll
  for (int k = 0; k < H; ++k) g += hs[wv][k] * W2[k * H + j];
  GA[(size_t)n * H + j] = g;
}

template<bool ACCUM>
__global__ void convN_kernel(const float* __restrict__ Gin, const float* __restrict__ dinv,
                             const int* __restrict__ rowptr, const int* __restrict__ csr_src,
                             const float* __restrict__ csr_norm, const float* __restrict__ b,
                             const float* __restrict__ Wnext, float* __restrict__ Gout) {
  __shared__ __align__(16) float hs[4][H];
  int tid = threadIdx.x;
  int wv = tid >> 6, lane = tid & 63;
  int sub = lane >> 4, q = lane & 15;
  int n = blockIdx.x * 4 + wv;
  float di = dinv[n];
  const float4* G4 = (const float4*)Gin;
  float4 a0 = {0,0,0,0}, a1 = {0,0,0,0};
  int e0 = rowptr[n], e1 = rowptr[n + 1];
  int e = e0 + sub;
  for (; e + 4 < e1; e += 8) {
    int s0 = csr_src[e];     float w0 = csr_norm[e];
    int s1 = csr_src[e + 4]; float w1 = csr_norm[e + 4];
    float4 r0 = G4[(size_t)s0 * 16 + q];
    float4 r1 = G4[(size_t)s1 * 16 + q];
    a0.x += w0 * r0.x; a0.y += w0 * r0.y; a0.z += w0 * r0.z; a0.w += w0 * r0.w;
    a1.x += w1 * r1.x; a1.y += w1 * r1.y; a1.z += w1 * r1.z; a1.w += w1 * r1.w;
  }
  for (; e < e1; e += 4) {
    int s0 = csr_src[e]; float w0 = csr_norm[e];
    float4 r0 = G4[(size_t)s0 * 16 + q];
    a0.x += w0 * r0.x; a0.y += w0 * r0.y; a0.z += w0 * r0.z; a0.w += w0 * r0.w;
  }
  a0.x += a1.x; a0.y += a1.y; a0.z += a1.z; a0.w += a1.w;
  #pragma unroll
  for (int off = 16; off <= 32; off <<= 1) {
    a0.x += __shfl_xor(a0.x, off, 64);
    a0.y += __shfl_xor(a0.y, off, 64);
    a0.z += __shfl_xor(a0.z, off, 64);
    a0.w += __shfl_xor(a0.w, off, 64);
  }
  float4 own = G4[(size_t)n * 16 + q];
  float dd = di * di;
  if (sub == 0) {
    float4 h;
    h.x = fmaxf(a0.x + dd * own.x + b[4 * q + 0], 0.f);
    h.y = fmaxf(a0.y + dd * own.y + b[4 * q + 1], 0.f);
    h.z = fmaxf(a0.z + dd * own.z + b[4 * q + 2], 0.f);
    h.w = fmaxf(a0.w + dd * own.w + b[4 * q + 3], 0.f);
    ((float4*)hs[wv])[q] = h;
  }
  __syncthreads();
  float g = 0.f;
  #pragma unroll
  for (int k = 0; k < H; ++k) g += hs[wv][k] * Wnext[k * H + lane];
  if (ACCUM) Gout[(size_t)n * H + lane] += g;
  else       Gout[(size_t)n * H + lane]  = g;
}

__global__ void final_kernel(const float* __restrict__ acc, const float* __restrict__ bseq,
                             const float* __restrict__ Wcls, const float* __restrict__ bcls,
                             float* __restrict__ out) {
  __shared__ float hs[4][H];
  int tid = threadIdx.x;
  int wv = tid >> 6, j = tid & 63;
  int n = blockIdx.x * 4 + wv;
  hs[wv][j] = fmaxf(acc[(size_t)n * H + j] + bseq[j], 0.0f);
  __syncthreads();
  if (j < C) {
    float o = bcls[j];
    #pragma unroll
    for (int k = 0; k < H; ++k) o += hs[wv][k] * Wcls[k * C + j];
    out[(size_t)n * C + j] = o;
  }
}

extern "C" void kernel_launch(void* const* d_in, const int* in_sizes, int n_in,
                              void* d_out, int out_size, void* d_ws, size_t ws_size,
                              hipStream_t stream) {
  const float* x    = (const float*)d_in[0];
  const int*   ei   = (const int*)  d_in[1];
  const float* w    = (const float*)d_in[2];
  const float* W1   = (const float*)d_in[3];
  const float* b1   = (const float*)d_in[4];
  const float* W2   = (const float*)d_in[5];
  const float* b2   = (const float*)d_in[6];
  const float* W3   = (const float*)d_in[7];
  const float* b3   = (const float*)d_in[8];
  const float* Wseq = (const float*)d_in[9];
  const float* bseq = (const float*)d_in[10];
  const float* Wcls = (const float*)d_in[11];
  const float* bcls = (const float*)d_in[12];
  float* out = (float*)d_out;

  char* p = (char*)d_ws;
  auto alloc = [&](size_t bytes) -> char* {
    char* r = p; p += (bytes + 255) & ~(size_t)255; return r;
  };
  float*  deg     = (float*) alloc((size_t)N * 4);      // becomes dinv
  int*    counts  = (int*)   alloc((size_t)N * 4);
  int*    fillc   = (int*)   alloc((size_t)N * 4);
  int*    rowptr  = (int*)   alloc((size_t)(N + 1) * 4);
  int*    csr_src = (int*)   alloc((size_t)E * 4);
  float*  csr_nrm = (float*) alloc((size_t)E * 4);
  float*  xagg    = (float*) alloc((size_t)N * 128 * 4);
  __half* xh      = (__half*)alloc((size_t)N * 128 * 2);

  hipMemsetAsync(deg,    0, (size_t)N * 4, stream);
  hipMemsetAsync(counts, 0, (size_t)N * 4, stream);
  hipMemsetAsync(fillc,  0, (size_t)N * 4, stream);

  cvt_x_kernel<<<(N * 32 + 255) / 256, 256, 0, stream>>>(x, xh);
  deg_count_kernel<<<(E + 255) / 256, 256, 0, stream>>>(ei, w, deg, counts);
  dinv_kernel<<<(N + 255) / 256, 256, 0, stream>>>(deg);
  scan_kernel<<<1, 1024, 0, stream>>>(counts, rowptr);
  fill_kernel<<<(E + 255) / 256, 256, 0, stream>>>(ei, w, deg, rowptr, fillc, csr_src, csr_nrm);
  sort_rows_kernel<<<N / 4, 256, 0, stream>>>(rowptr, csr_src, csr_nrm);
  agg_x_kernel<<<N / 4, 256, 0, stream>>>(xh, deg, rowptr, csr_src, csr_nrm, xagg);

  // wide needs: common 52MB + G2h 51.2MB + G3h 51.2MB ~= 154.6MB
  bool wide = ws_size >= (size_t)155 * 1000 * 1000;

  if (wide) {
    __half* G2h = (__half*)alloc((size_t)N * 512 * 2);
    __half* G3h = (__half*)alloc((size_t)N * 512 * 2);
    dense12_kernel<<<N / 4, 256, 0, stream>>>(xagg, W1, b1, W2, G2h);
    conv2w_kernel<<<N / 4, 256, 0, stream>>>(G2h, deg, rowptr, csr_src, csr_nrm, b2, W3, G3h);
    conv3w_kernel<<<N / 4, 256, 0, stream>>>(G3h, deg, rowptr, csr_src, csr_nrm, b3,
                                             Wseq, bseq, Wcls, bcls, out);
  } else {
    float* GA  = (float*)alloc((size_t)N * H * 4);
    float* GB  = (float*)alloc((size_t)N * H * 4);
    float* acc = (float*)alloc((size_t)N * H * 4);
    hipMemsetAsync(acc, 0, (size_t)N * H * 4, stream);
    for (int t = 0; t < T; ++t) {
      layer1N_kernel<<<N / 4, 256, 0, stream>>>(xagg, W1, b1, W2, GA, t);
      convN_kernel<false><<<N / 4, 256, 0, stream>>>(GA, deg, rowptr, csr_src, csr_nrm, b2, W3, GB);
      convN_kernel<true ><<<N / 4, 256, 0, stream>>>(GB, deg, rowptr, csr_src, csr_nrm, b3,
                                                     Wseq + (size_t)t * H * H, acc);
    }
    final_kernel<<<N / 4, 256, 0, stream>>>(acc, bseq, Wcls, bcls, out);
  }
}

// Round 6
// 923.817 us; speedup vs baseline: 1.0503x; 1.0503x over previous
//
#include <hip/hip_runtime.h>
#include <hip/hip_fp16.h>

constexpr int N  = 50000;
constexpr int E  = 1600000;
constexpr int T  = 8;
constexpr int H  = 64;
constexpr int C  = 10;

// ---------------- degree + histogram ----------------
__global__ void deg_count_kernel(const int* __restrict__ ei, const float* __restrict__ w,
                                 float* __restrict__ deg, int* __restrict__ counts) {
  int e = blockIdx.x * blockDim.x + threadIdx.x;
  if (e >= E) return;
  int d = ei[E + e];
  atomicAdd(&deg[d], w[e]);
  atomicAdd(&counts[d], 1);
}

__global__ void dinv_kernel(float* deg) {
  int n = blockIdx.x * blockDim.x + threadIdx.x;
  if (n >= N) return;
  deg[n] = rsqrtf(deg[n] + 1.0f);  // +1 = self-loop weight
}

// ---------------- exclusive scan (single block, 1024 threads) ----------------
__global__ void scan_kernel(const int* __restrict__ counts, int* __restrict__ rowptr) {
  __shared__ int wsum[16];
  __shared__ int carry_s;
  int tid = threadIdx.x;
  if (tid == 0) carry_s = 0;
  __syncthreads();
  for (int base = 0; base < N; base += 1024) {
    int i = base + tid;
    int v = (i < N) ? counts[i] : 0;
    int x = v;
    #pragma unroll
    for (int off = 1; off < 64; off <<= 1) {
      int y = __shfl_up(x, off, 64);
      if ((tid & 63) >= off) x += y;
    }
    if ((tid & 63) == 63) wsum[tid >> 6] = x;
    __syncthreads();
    if (tid < 16) {
      int wv = wsum[tid];
      #pragma unroll
      for (int off = 1; off < 16; off <<= 1) {
        int y = __shfl_up(wv, off, 16);
        if (tid >= off) wv += y;
      }
      wsum[tid] = wv;
    }
    __syncthreads();
    int carry = carry_s;
    int waveoff = (tid >> 6) ? wsum[(tid >> 6) - 1] : 0;
    int inc = x + waveoff + carry;
    if (i < N) rowptr[i + 1] = inc;
    __syncthreads();
    if (tid == 1023) carry_s = inc;
    __syncthreads();
  }
  if (tid == 0) rowptr[0] = 0;
}

// ---------------- CSR fill (int2 meta: {src, norm-bits}) ----------------
__global__ void fill_kernel(const int* __restrict__ ei, const float* __restrict__ w,
                            const float* __restrict__ dinv, const int* __restrict__ rowptr,
                            int* __restrict__ fill, int2* __restrict__ csr_meta) {
  int e = blockIdx.x * blockDim.x + threadIdx.x;
  if (e >= E) return;
  int s = ei[e], d = ei[E + e];
  int pos = rowptr[d] + atomicAdd(&fill[d], 1);
  int2 m;
  m.x = s;
  m.y = __float_as_int(dinv[s] * w[e] * dinv[d]);
  csr_meta[pos] = m;
}

// ---------------- x (fp32) -> xh (fp16) ----------------
__global__ void cvt_x_kernel(const float* __restrict__ x, __half* __restrict__ xh) {
  int i = blockIdx.x * blockDim.x + threadIdx.x;  // over N*32 float4s
  if (i >= N * 32) return;
  float4 v = ((const float4*)x)[i];
  __half2 h0; h0.x = __float2half_rn(v.x); h0.y = __float2half_rn(v.y);
  __half2 h1; h1.x = __float2half_rn(v.z); h1.y = __float2half_rn(v.w);
  uint2 u;
  u.x = __builtin_bit_cast(unsigned int, h0);
  u.y = __builtin_bit_cast(unsigned int, h1);
  ((uint2*)xh)[i] = u;
}

// ---------------- xagg = Ahat @ X, fp16 256B rows, wave/node, 4-deep pipeline ----------------
__global__ void agg_x_kernel(const __half* __restrict__ xh, const float* __restrict__ dinv,
                             const int* __restrict__ rowptr, const int2* __restrict__ csr_meta,
                             float* __restrict__ xagg) {
  int tid = threadIdx.x;
  int w = tid >> 6, l = tid & 63;
  int sub = l >> 4, q = l & 15;      // 4 slots x 16 lanes x 16B = 256B row each
  int n = blockIdx.x * 4 + w;
  float di = dinv[n], dd = di * di;
  int e0 = rowptr[n], e1 = rowptr[n + 1];
  int cnt = e1 - e0 + 1;             // item 0 = self
  float acc[8] = {0, 0, 0, 0, 0, 0, 0, 0};
  int sA; float wA;
  {
    int idx = sub;
    if (idx == 0)       { sA = n; wA = dd; }
    else if (idx < cnt) { int2 m = csr_meta[e0 + idx - 1]; sA = m.x; wA = __int_as_float(m.y); }
    else                { sA = n; wA = 0.f; }
  }
  for (int i = sub; i < cnt; i += 4) {
    uint4 r = *reinterpret_cast<const uint4*>(xh + (size_t)sA * 128 + q * 8);
    int idx = i + 4;
    if (idx < cnt) { int2 m = csr_meta[e0 + idx - 1]; sA = m.x; wA = __int_as_float(m.y); }
    else           { sA = n; wA = 0.f; }
    float2 f0 = __half22float2(__builtin_bit_cast(__half2, r.x));
    float2 f1 = __half22float2(__builtin_bit_cast(__half2, r.y));
    float2 f2 = __half22float2(__builtin_bit_cast(__half2, r.z));
    float2 f3 = __half22float2(__builtin_bit_cast(__half2, r.w));
    float wgt = (i == 0 && sub == 0) ? dd : wA;
    // note: wA was already consumed into r's weight; use the weight paired with r:
    (void)wgt;
    // The weight for r is the one loaded BEFORE r was issued; keep it in a temp:
    // (restructured below to keep pairing correct)
    acc[0] = acc[0]; // no-op placeholder removed by compiler
    float wr = 0.f;
    (void)wr;
    // -- actual accumulation done with the weight captured before the load:
    // (we re-fetch from the loop-carried pair)
    // see wPair below
    f0 = f0; f1 = f1; f2 = f2; f3 = f3;
    break; // placeholder — replaced by correct loop below
  }
  // ---- correct 4-deep loop (weight/row pairing kept explicitly) ----
  {
    int sCur; float wCur;
    int idx0 = sub;
    if (idx0 == 0)       { sCur = n; wCur = dd; }
    else if (idx0 < cnt) { int2 m = csr_meta[e0 + idx0 - 1]; sCur = m.x; wCur = __int_as_float(m.y); }
    else                 { sCur = n; wCur = 0.f; }
    acc[0] = acc[1] = acc[2] = acc[3] = acc[4] = acc[5] = acc[6] = acc[7] = 0.f;
    for (int i = sub; i < cnt; i += 4) {
      uint4 r = *reinterpret_cast<const uint4*>(xh + (size_t)sCur * 128 + q * 8);
      float wUse = wCur;
      int idx = i + 4;
      if (idx < cnt) { int2 m = csr_meta[e0 + idx - 1]; sCur = m.x; wCur = __int_as_float(m.y); }
      else           { sCur = n; wCur = 0.f; }
      float2 f0 = __half22float2(__builtin_bit_cast(__half2, r.x));
      float2 f1 = __half22float2(__builtin_bit_cast(__half2, r.y));
      float2 f2 = __half22float2(__builtin_bit_cast(__half2, r.z));
      float2 f3 = __half22float2(__builtin_bit_cast(__half2, r.w));
      acc[0] = fmaf(wUse, f0.x, acc[0]); acc[1] = fmaf(wUse, f0.y, acc[1]);
      acc[2] = fmaf(wUse, f1.x, acc[2]); acc[3] = fmaf(wUse, f1.y, acc[3]);
      acc[4] = fmaf(wUse, f2.x, acc[4]); acc[5] = fmaf(wUse, f2.y, acc[5]);
      acc[6] = fmaf(wUse, f3.x, acc[6]); acc[7] = fmaf(wUse, f3.y, acc[7]);
    }
  }
  #pragma unroll
  for (int v = 0; v < 8; ++v) {
    acc[v] += __shfl_xor(acc[v], 16, 64);
    acc[v] += __shfl_xor(acc[v], 32, 64);
  }
  if (sub == 0) {
    float4 o0; o0.x = acc[0]; o0.y = acc[1]; o0.z = acc[2]; o0.w = acc[3];
    float4 o1; o1.x = acc[4]; o1.y = acc[5]; o1.z = acc[6]; o1.w = acc[7];
    float4* dst = (float4*)(xagg + (size_t)n * 128 + q * 8);
    dst[0] = o0; dst[1] = o1;
  }
}

// ---------------- dense: h1 = relu(xagg_t @ W1 + b1); G2 = h1 @ W2 (fp16, all t) ----------------
__global__ void dense12_kernel(const float* __restrict__ xagg, const float* __restrict__ W1,
                               const float* __restrict__ b1, const float* __restrict__ W2,
                               __half* __restrict__ G2h) {
  __shared__ float xs[4 * 128];
  __shared__ float h1s[4][8][64];
  int tid = threadIdx.x;
  int n0 = blockIdx.x * 4;
  ((float2*)xs)[tid] = ((const float2*)(xagg + (size_t)n0 * 128))[tid];
  __syncthreads();
  int nb = tid >> 6, j = tid & 63;
  float a[8];
  float bj = b1[j];
  #pragma unroll
  for (int t = 0; t < 8; ++t) a[t] = bj;
  for (int f = 0; f < 16; ++f) {
    float wv = W1[f * 64 + j];
    #pragma unroll
    for (int t = 0; t < 8; ++t) a[t] = fmaf(xs[nb * 128 + f * 8 + t], wv, a[t]);
  }
  #pragma unroll
  for (int t = 0; t < 8; ++t) h1s[nb][t][j] = fmaxf(a[t], 0.f);
  __syncthreads();
  float g[8];
  #pragma unroll
  for (int t = 0; t < 8; ++t) g[t] = 0.f;
  for (int k = 0; k < 64; ++k) {
    float wv = W2[k * 64 + j];
    #pragma unroll
    for (int t = 0; t < 8; ++t) g[t] = fmaf(h1s[nb][t][k], wv, g[t]);
  }
  __half* gp = G2h + (size_t)(n0 + nb) * 512 + j;
  #pragma unroll
  for (int t = 0; t < 8; ++t) gp[t * 64] = __float2half_rn(g[t]);
}

// 8-halves fused accumulate helper
__device__ __forceinline__ void accum8(float* acc, uint4 r, float wgt) {
  float2 f0 = __half22float2(__builtin_bit_cast(__half2, r.x));
  float2 f1 = __half22float2(__builtin_bit_cast(__half2, r.y));
  float2 f2 = __half22float2(__builtin_bit_cast(__half2, r.z));
  float2 f3 = __half22float2(__builtin_bit_cast(__half2, r.w));
  acc[0] = fmaf(wgt, f0.x, acc[0]); acc[1] = fmaf(wgt, f0.y, acc[1]);
  acc[2] = fmaf(wgt, f1.x, acc[2]); acc[3] = fmaf(wgt, f1.y, acc[3]);
  acc[4] = fmaf(wgt, f2.x, acc[4]); acc[5] = fmaf(wgt, f2.y, acc[5]);
  acc[6] = fmaf(wgt, f3.x, acc[6]); acc[7] = fmaf(wgt, f3.y, acc[7]);
}

// ---------------- conv2: aggregate G2h (1KB fp16 rows, 4-deep pipeline); h2=relu(+b2); G3h = h2 @ W3 ----------------
__global__ void conv2w_kernel(const __half* __restrict__ G2h, const float* __restrict__ dinv,
                              const int* __restrict__ rowptr, const int2* __restrict__ csr_meta,
                              const float* __restrict__ b2,
                              const float* __restrict__ W3, __half* __restrict__ G3h) {
  __shared__ float h2s[4][512];
  int tid = threadIdx.x;
  int w = tid >> 6, l = tid & 63;
  int n0 = blockIdx.x * 4;
  int n = n0 + w;
  float di = dinv[n], dd = di * di;
  int e0 = rowptr[n], e1 = rowptr[n + 1];
  int cnt = e1 - e0 + 1;             // item 0 = self
  float acc[8] = {0, 0, 0, 0, 0, 0, 0, 0};
  int sm[4]; float wm[4];
  #pragma unroll
  for (int q = 0; q < 4; ++q) {
    int idx = q;
    if (idx == 0)       { sm[q] = n; wm[q] = dd; }
    else if (idx < cnt) { int2 m = csr_meta[e0 + idx - 1]; sm[q] = m.x; wm[q] = __int_as_float(m.y); }
    else                { sm[q] = n; wm[q] = 0.f; }
  }
  for (int i = 0; i < cnt; i += 4) {
    uint4 r0 = *reinterpret_cast<const uint4*>(G2h + (size_t)sm[0] * 512 + l * 8);
    uint4 r1 = *reinterpret_cast<const uint4*>(G2h + (size_t)sm[1] * 512 + l * 8);
    uint4 r2 = *reinterpret_cast<const uint4*>(G2h + (size_t)sm[2] * 512 + l * 8);
    uint4 r3 = *reinterpret_cast<const uint4*>(G2h + (size_t)sm[3] * 512 + l * 8);
    float w0 = wm[0], w1 = wm[1], w2 = wm[2], w3 = wm[3];
    #pragma unroll
    for (int q = 0; q < 4; ++q) {
      int idx = i + 4 + q;           // >= 4, never self
      if (idx < cnt) { int2 m = csr_meta[e0 + idx - 1]; sm[q] = m.x; wm[q] = __int_as_float(m.y); }
      else           { sm[q] = n; wm[q] = 0.f; }
    }
    accum8(acc, r0, w0);
    accum8(acc, r1, w1);
    accum8(acc, r2, w2);
    accum8(acc, r3, w3);
  }
  #pragma unroll
  for (int q = 0; q < 8; ++q)
    h2s[w][l * 8 + q] = fmaxf(acc[q] + b2[(l * 8 + q) & 63], 0.f);
  __syncthreads();
  // per-t dense: G3[t*64 + j] = sum_k h2[t*64+k] * W3[k][j]
  int t = tid >> 5;            // 0..7
  int jh = tid & 31, j0 = 2 * jh;
  float g[4][2];
  #pragma unroll
  for (int q = 0; q < 4; ++q) { g[q][0] = 0.f; g[q][1] = 0.f; }
  const float2* W3v = (const float2*)W3;
  for (int k = 0; k < 64; ++k) {
    float2 wv = W3v[k * 32 + jh];
    #pragma unroll
    for (int q = 0; q < 4; ++q) {
      float h = h2s[q][t * 64 + k];
      g[q][0] = fmaf(h, wv.x, g[q][0]);
      g[q][1] = fmaf(h, wv.y, g[q][1]);
    }
  }
  #pragma unroll
  for (int q = 0; q < 4; ++q) {
    __half2 hv;
    hv.x = __float2half_rn(g[q][0]);
    hv.y = __float2half_rn(g[q][1]);
    *reinterpret_cast<__half2*>(G3h + (size_t)(n0 + q) * 512 + t * 64 + j0) = hv;
  }
}

// ---------------- conv3 + head: aggregate G3h (4-deep); h3=relu(+b3); out = relu(h3@Wseq+bseq)@Wcls+bcls ----------------
__global__ void conv3w_kernel(const __half* __restrict__ G3h, const float* __restrict__ dinv,
                              const int* __restrict__ rowptr, const int2* __restrict__ csr_meta,
                              const float* __restrict__ b3,
                              const float* __restrict__ Wseq, const float* __restrict__ bseq,
                              const float* __restrict__ Wcls, const float* __restrict__ bcls,
                              float* __restrict__ out) {
  __shared__ float h3s[4][512];
  __shared__ float red[4][4][64];
  __shared__ float hfs[4][64];
  int tid = threadIdx.x;
  int w = tid >> 6, l = tid & 63;
  int n0 = blockIdx.x * 4;
  int n = n0 + w;
  float di = dinv[n], dd = di * di;
  int e0 = rowptr[n], e1 = rowptr[n + 1];
  int cnt = e1 - e0 + 1;
  float acc[8] = {0, 0, 0, 0, 0, 0, 0, 0};
  int sm[4]; float wm[4];
  #pragma unroll
  for (int q = 0; q < 4; ++q) {
    int idx = q;
    if (idx == 0)       { sm[q] = n; wm[q] = dd; }
    else if (idx < cnt) { int2 m = csr_meta[e0 + idx - 1]; sm[q] = m.x; wm[q] = __int_as_float(m.y); }
    else                { sm[q] = n; wm[q] = 0.f; }
  }
  for (int i = 0; i < cnt; i += 4) {
    uint4 r0 = *reinterpret_cast<const uint4*>(G3h + (size_t)sm[0] * 512 + l * 8);
    uint4 r1 = *reinterpret_cast<const uint4*>(G3h + (size_t)sm[1] * 512 + l * 8);
    uint4 r2 = *reinterpret_cast<const uint4*>(G3h + (size_t)sm[2] * 512 + l * 8);
    uint4 r3 = *reinterpret_cast<const uint4*>(G3h + (size_t)sm[3] * 512 + l * 8);
    float w0 = wm[0], w1 = wm[1], w2 = wm[2], w3 = wm[3];
    #pragma unroll
    for (int q = 0; q < 4; ++q) {
      int idx = i + 4 + q;
      if (idx < cnt) { int2 m = csr_meta[e0 + idx - 1]; sm[q] = m.x; wm[q] = __int_as_float(m.y); }
      else           { sm[q] = n; wm[q] = 0.f; }
    }
    accum8(acc, r0, w0);
    accum8(acc, r1, w1);
    accum8(acc, r2, w2);
    accum8(acc, r3, w3);
  }
  #pragma unroll
  for (int q = 0; q < 8; ++q)
    h3s[w][l * 8 + q] = fmaxf(acc[q] + b3[(l * 8 + q) & 63], 0.f);
  __syncthreads();
  // seq contraction: partial[p][nb][j] = sum_{c in p-range} h3[nb][c] * Wseq[c][j]
  int p = tid >> 6, j = tid & 63;
  float pa0 = 0.f, pa1 = 0.f, pa2 = 0.f, pa3 = 0.f;
  for (int ci = 0; ci < 128; ++ci) {
    int c = p * 128 + ci;
    float wv = Wseq[(size_t)c * 64 + j];
    pa0 = fmaf(h3s[0][c], wv, pa0);
    pa1 = fmaf(h3s[1][c], wv, pa1);
    pa2 = fmaf(h3s[2][c], wv, pa2);
    pa3 = fmaf(h3s[3][c], wv, pa3);
  }
  red[p][0][j] = pa0; red[p][1][j] = pa1; red[p][2][j] = pa2; red[p][3][j] = pa3;
  __syncthreads();
  int nb = tid >> 6, k = tid & 63;
  float s = red[0][nb][k] + red[1][nb][k] + red[2][nb][k] + red[3][nb][k] + bseq[k];
  hfs[nb][k] = fmaxf(s, 0.f);
  __syncthreads();
  if (k < C) {
    float o = bcls[k];
    #pragma unroll
    for (int kk = 0; kk < 64; ++kk) o = fmaf(hfs[nb][kk], Wcls[kk * C + k], o);
    out[(size_t)(n0 + nb) * C + k] = o;
  }
}

// ================= NARROW FALLBACK (fp32, per-t) =================
__global__ void layer1N_kernel(const float* __restrict__ xagg, const float* __restrict__ W1,
                               const float* __restrict__ b1, const float* __restrict__ W2,
                               float* __restrict__ GA, int t) {
  __shared__ float hs[4][H];
  int tid = threadIdx.x;
  int wv = tid >> 6, j = tid & 63;
  int n = blockIdx.x * 4 + wv;
  const float* xa = xagg + (size_t)n * 128;
  float a = b1[j];
  #pragma unroll
  for (int f = 0; f < 16; ++f) a += xa[f * 8 + t] * W1[f * H + j];
  hs[wv][j] = fmaxf(a, 0.f);
  __syncthreads();
  float g = 0.f;
  #pragma unroll
  for (int k = 0; k < H; ++k) g += hs[wv][k] * W2[k * H + j];
  GA[(size_t)n * H + j] = g;
}

template<bool ACCUM>
__global__ void convN_kernel(const float* __restrict__ Gin, const float* __restrict__ dinv,
                             const int* __restrict__ rowptr, const int2* __restrict__ csr_meta,
                             const float* __restrict__ b,
                             const float* __restrict__ Wnext, float* __restrict__ Gout) {
  __shared__ __align__(16) float hs[4][H];
  int tid = threadIdx.x;
  int wv = tid >> 6, lane = tid & 63;
  int sub = lane >> 4, q = lane & 15;
  int n = blockIdx.x * 4 + wv;
  float di = dinv[n];
  const float4* G4 = (const float4*)Gin;
  float4 a0 = {0,0,0,0};
  int e0 = rowptr[n], e1 = rowptr[n + 1];
  for (int e = e0 + sub; e < e1; e += 4) {
    int2 m = csr_meta[e];
    float w0 = __int_as_float(m.y);
    float4 r0 = G4[(size_t)m.x * 16 + q];
    a0.x += w0 * r0.x; a0.y += w0 * r0.y; a0.z += w0 * r0.z; a0.w += w0 * r0.w;
  }
  #pragma unroll
  for (int off = 16; off <= 32; off <<= 1) {
    a0.x += __shfl_xor(a0.x, off, 64);
    a0.y += __shfl_xor(a0.y, off, 64);
    a0.z += __shfl_xor(a0.z, off, 64);
    a0.w += __shfl_xor(a0.w, off, 64);
  }
  float4 own = G4[(size_t)n * 16 + q];
  float dd = di * di;
  if (sub == 0) {
    float4 h;
    h.x = fmaxf(a0.x + dd * own.x + b[4 * q + 0], 0.f);
    h.y = fmaxf(a0.y + dd * own.y + b[4 * q + 1], 0.f);
    h.z = fmaxf(a0.z + dd * own.z + b[4 * q + 2], 0.f);
    h.w = fmaxf(a0.w + dd * own.w + b[4 * q + 3], 0.f);
    ((float4*)hs[wv])[q] = h;
  }
  __syncthreads();
  float g = 0.f;
  #pragma unroll
  for (int k = 0; k < H; ++k) g += hs[wv][k] * Wnext[k * H + lane];
  if (ACCUM) Gout[(size_t)n * H + lane] += g;
  else       Gout[(size_t)n * H + lane]  = g;
}

__global__ void final_kernel(const float* __restrict__ acc, const float* __restrict__ bseq,
                             const float* __restrict__ Wcls, const float* __restrict__ bcls,
                             float* __restrict__ out) {
  __shared__ float hs[4][H];
  int tid = threadIdx.x;
  int wv = tid >> 6, j = tid & 63;
  int n = blockIdx.x * 4 + wv;
  hs[wv][j] = fmaxf(acc[(size_t)n * H + j] + bseq[j], 0.0f);
  __syncthreads();
  if (j < C) {
    float o = bcls[j];
    #pragma unroll
    for (int k = 0; k < H; ++k) o += hs[wv][k] * Wcls[k * C + j];
    out[(size_t)n * C + j] = o;
  }
}

extern "C" void kernel_launch(void* const* d_in, const int* in_sizes, int n_in,
                              void* d_out, int out_size, void* d_ws, size_t ws_size,
                              hipStream_t stream) {
  const float* x    = (const float*)d_in[0];
  const int*   ei   = (const int*)  d_in[1];
  const float* w    = (const float*)d_in[2];
  const float* W1   = (const float*)d_in[3];
  const float* b1   = (const float*)d_in[4];
  const float* W2   = (const float*)d_in[5];
  const float* b2   = (const float*)d_in[6];
  const float* W3   = (const float*)d_in[7];
  const float* b3   = (const float*)d_in[8];
  const float* Wseq = (const float*)d_in[9];
  const float* bseq = (const float*)d_in[10];
  const float* Wcls = (const float*)d_in[11];
  const float* bcls = (const float*)d_in[12];
  float* out = (float*)d_out;

  char* p = (char*)d_ws;
  auto alloc = [&](size_t bytes) -> char* {
    char* r = p; p += (bytes + 255) & ~(size_t)255; return r;
  };
  float*  deg     = (float*) alloc((size_t)N * 4);      // becomes dinv
  int*    counts  = (int*)   alloc((size_t)N * 4);
  int*    fillc   = (int*)   alloc((size_t)N * 4);
  int*    rowptr  = (int*)   alloc((size_t)(N + 1) * 4);
  int2*   csr_meta= (int2*)  alloc((size_t)E * 8);
  float*  xagg    = (float*) alloc((size_t)N * 128 * 4);
  __half* xh      = (__half*)alloc((size_t)N * 128 * 2);

  hipMemsetAsync(deg,    0, (size_t)N * 4, stream);
  hipMemsetAsync(counts, 0, (size_t)N * 4, stream);
  hipMemsetAsync(fillc,  0, (size_t)N * 4, stream);

  cvt_x_kernel<<<(N * 32 + 255) / 256, 256, 0, stream>>>(x, xh);
  deg_count_kernel<<<(E + 255) / 256, 256, 0, stream>>>(ei, w, deg, counts);
  dinv_kernel<<<(N + 255) / 256, 256, 0, stream>>>(deg);
  scan_kernel<<<1, 1024, 0, stream>>>(counts, rowptr);
  fill_kernel<<<(E + 255) / 256, 256, 0, stream>>>(ei, w, deg, rowptr, fillc, csr_meta);
  agg_x_kernel<<<N / 4, 256, 0, stream>>>(xh, deg, rowptr, csr_meta, xagg);

  // wide needs: common 52MB + G2h 51.2MB + G3h 51.2MB ~= 155MB
  bool wide = ws_size >= (size_t)155 * 1000 * 1000;

  if (wide) {
    __half* G2h = (__half*)alloc((size_t)N * 512 * 2);
    __half* G3h = (__half*)alloc((size_t)N * 512 * 2);
    dense12_kernel<<<N / 4, 256, 0, stream>>>(xagg, W1, b1, W2, G2h);
    conv2w_kernel<<<N / 4, 256, 0, stream>>>(G2h, deg, rowptr, csr_meta, b2, W3, G3h);
    conv3w_kernel<<<N / 4, 256, 0, stream>>>(G3h, deg, rowptr, csr_meta, b3,
                                             Wseq, bseq, Wcls, bcls, out);
  } else {
    float* GA  = (float*)alloc((size_t)N * H * 4);
    float* GB  = (float*)alloc((size_t)N * H * 4);
    float* acc = (float*)alloc((size_t)N * H * 4);
    hipMemsetAsync(acc, 0, (size_t)N * H * 4, stream);
    for (int t = 0; t < T; ++t) {
      layer1N_kernel<<<N / 4, 256, 0, stream>>>(xagg, W1, b1, W2, GA, t);
      convN_kernel<false><<<N / 4, 256, 0, stream>>>(GA, deg, rowptr, csr_meta, b2, W3, GB);
      convN_kernel<true ><<<N / 4, 256, 0, stream>>>(GB, deg, rowptr, csr_meta, b3,
                                                     Wseq + (size_t)t * H * H, acc);
    }
    final_kernel<<<N / 4, 256, 0, stream>>>(acc, bseq, Wcls, bcls, out);
  }
}

// Round 7
// 836.229 us; speedup vs baseline: 1.1603x; 1.1047x over previous
//
#include <hip/hip_runtime.h>
#include <hip/hip_fp16.h>

constexpr int N  = 50000;
constexpr int E  = 1600000;
constexpr int T  = 8;
constexpr int H  = 64;
constexpr int C  = 10;

// ---------------- degree + histogram ----------------
__global__ void deg_count_kernel(const int* __restrict__ ei, const float* __restrict__ w,
                                 float* __restrict__ deg, int* __restrict__ counts) {
  int e = blockIdx.x * blockDim.x + threadIdx.x;
  if (e >= E) return;
  int d = ei[E + e];
  atomicAdd(&deg[d], w[e]);
  atomicAdd(&counts[d], 1);
}

__global__ void dinv_kernel(float* deg) {
  int n = blockIdx.x * blockDim.x + threadIdx.x;
  if (n >= N) return;
  deg[n] = rsqrtf(deg[n] + 1.0f);  // +1 = self-loop weight
}

// ---------------- two-level scan: A (per-1024-tile), B (tile sums), C (add offsets) ----------------
__global__ void scanA_kernel(const int* __restrict__ counts, int* __restrict__ rowptr,
                             int* __restrict__ bsum) {
  __shared__ int ws[4];
  int b = blockIdx.x, t = threadIdx.x;
  int base = b * 1024 + t * 4;
  int v0 = (base + 0 < N) ? counts[base + 0] : 0;
  int v1 = (base + 1 < N) ? counts[base + 1] : 0;
  int v2 = (base + 2 < N) ? counts[base + 2] : 0;
  int v3 = (base + 3 < N) ? counts[base + 3] : 0;
  int s = v0 + v1 + v2 + v3;
  int lane = t & 63, wid = t >> 6;
  int x = s;
  #pragma unroll
  for (int off = 1; off < 64; off <<= 1) {
    int y = __shfl_up(x, off, 64);
    if (lane >= off) x += y;
  }
  if (lane == 63) ws[wid] = x;
  __syncthreads();
  int woff = 0;
  #pragma unroll
  for (int k = 0; k < 4; ++k) if (k < wid) woff += ws[k];
  int excl = x + woff - s;   // exclusive prefix of this thread's 4 elements within tile
  int a = excl;
  a += v0; if (base + 0 < N) rowptr[base + 1] = a;
  a += v1; if (base + 1 < N) rowptr[base + 2] = a;
  a += v2; if (base + 2 < N) rowptr[base + 3] = a;
  a += v3; if (base + 3 < N) rowptr[base + 4] = a;
  if (t == 255) bsum[b] = x + woff;   // tile total
}

__global__ void scanB_kernel(const int* __restrict__ bsum, int* __restrict__ boff, int nb) {
  int t = threadIdx.x;   // 64 threads
  int v = (t < nb) ? bsum[t] : 0;
  int x = v;
  #pragma unroll
  for (int off = 1; off < 64; off <<= 1) {
    int y = __shfl_up(x, off, 64);
    if (t >= off) x += y;
  }
  if (t < nb) boff[t] = x - v;   // exclusive
}

__global__ void scanC_kernel(int* __restrict__ rowptr, const int* __restrict__ boff) {
  int i = blockIdx.x * 256 + threadIdx.x;
  if (i == 0) rowptr[0] = 0;
  if (i < N) rowptr[i + 1] += boff[i >> 10];
}

// ---------------- CSR fill (split arrays — wave-uniform scalar loads in gathers) ----------------
__global__ void fill_kernel(const int* __restrict__ ei, const float* __restrict__ w,
                            const float* __restrict__ dinv, const int* __restrict__ rowptr,
                            int* __restrict__ fill, int* __restrict__ csr_src,
                            float* __restrict__ csr_norm) {
  int e = blockIdx.x * blockDim.x + threadIdx.x;
  if (e >= E) return;
  int s = ei[e], d = ei[E + e];
  int pos = rowptr[d] + atomicAdd(&fill[d], 1);
  csr_src[pos] = s;
  csr_norm[pos] = dinv[s] * w[e] * dinv[d];
}

// ---------------- x (fp32) -> xh (fp16) ----------------
__global__ void cvt_x_kernel(const float* __restrict__ x, __half* __restrict__ xh) {
  int i = blockIdx.x * blockDim.x + threadIdx.x;  // over N*32 float4s
  if (i >= N * 32) return;
  float4 v = ((const float4*)x)[i];
  __half2 h0; h0.x = __float2half_rn(v.x); h0.y = __float2half_rn(v.y);
  __half2 h1; h1.x = __float2half_rn(v.z); h1.y = __float2half_rn(v.w);
  uint2 u;
  u.x = __builtin_bit_cast(unsigned int, h0);
  u.y = __builtin_bit_cast(unsigned int, h1);
  ((uint2*)xh)[i] = u;
}

// 8-halves fused accumulate helper
__device__ __forceinline__ void accum8(float* acc, uint4 r, float wgt) {
  float2 f0 = __half22float2(__builtin_bit_cast(__half2, r.x));
  float2 f1 = __half22float2(__builtin_bit_cast(__half2, r.y));
  float2 f2 = __half22float2(__builtin_bit_cast(__half2, r.z));
  float2 f3 = __half22float2(__builtin_bit_cast(__half2, r.w));
  acc[0] = fmaf(wgt, f0.x, acc[0]); acc[1] = fmaf(wgt, f0.y, acc[1]);
  acc[2] = fmaf(wgt, f1.x, acc[2]); acc[3] = fmaf(wgt, f1.y, acc[3]);
  acc[4] = fmaf(wgt, f2.x, acc[4]); acc[5] = fmaf(wgt, f2.y, acc[5]);
  acc[6] = fmaf(wgt, f3.x, acc[6]); acc[7] = fmaf(wgt, f3.y, acc[7]);
}

// ---------------- xagg = Ahat @ X, fp16 256B rows; 4 groups x 2-deep = 8 rows in flight ----------------
__global__ void agg_x_kernel(const __half* __restrict__ xh, const float* __restrict__ dinv,
                             const int* __restrict__ rowptr, const int* __restrict__ csr_src,
                             const float* __restrict__ csr_norm, float* __restrict__ xagg) {
  int tid = threadIdx.x;
  int w = tid >> 6, l = tid & 63;
  int sub = l >> 4, q = l & 15;      // 4 groups x 16 lanes; lane covers 16B of 256B row
  int n = blockIdx.x * 4 + w;
  float di = dinv[n], dd = di * di;
  int e0 = rowptr[n], e1 = rowptr[n + 1];
  int cnt = e1 - e0 + 1;             // item 0 = self
  float acc[8] = {0, 0, 0, 0, 0, 0, 0, 0};
  int sA, sB; float wA, wB;
  auto meta = [&](int idx, int& s_, float& w_) {
    if (idx == 0)       { s_ = n; w_ = dd; }
    else if (idx < cnt) { s_ = csr_src[e0 + idx - 1]; w_ = csr_norm[e0 + idx - 1]; }
    else                { s_ = n; w_ = 0.f; }
  };
  meta(sub,     sA, wA);
  meta(sub + 4, sB, wB);
  for (int i = sub; i < cnt; i += 8) {
    uint4 rA = *reinterpret_cast<const uint4*>(xh + (size_t)sA * 128 + q * 8);
    uint4 rB = *reinterpret_cast<const uint4*>(xh + (size_t)sB * 128 + q * 8);
    float uA = wA, uB = wB;
    meta(i + 8,  sA, wA);
    meta(i + 12, sB, wB);
    accum8(acc, rA, uA);
    accum8(acc, rB, uB);
  }
  #pragma unroll
  for (int v = 0; v < 8; ++v) {
    acc[v] += __shfl_xor(acc[v], 16, 64);
    acc[v] += __shfl_xor(acc[v], 32, 64);
  }
  if (sub == 0) {
    float4 o0; o0.x = acc[0]; o0.y = acc[1]; o0.z = acc[2]; o0.w = acc[3];
    float4 o1; o1.x = acc[4]; o1.y = acc[5]; o1.z = acc[6]; o1.w = acc[7];
    float4* dst = (float4*)(xagg + (size_t)n * 128 + q * 8);
    dst[0] = o0; dst[1] = o1;
  }
}

// ---------------- dense: h1 = relu(xagg_t @ W1 + b1); G2 = h1 @ W2 (fp16, all t) ----------------
__global__ void dense12_kernel(const float* __restrict__ xagg, const float* __restrict__ W1,
                               const float* __restrict__ b1, const float* __restrict__ W2,
                               __half* __restrict__ G2h) {
  __shared__ float xs[4 * 128];
  __shared__ float h1s[4][8][64];
  int tid = threadIdx.x;
  int n0 = blockIdx.x * 4;
  ((float2*)xs)[tid] = ((const float2*)(xagg + (size_t)n0 * 128))[tid];
  __syncthreads();
  int nb = tid >> 6, j = tid & 63;
  float a[8];
  float bj = b1[j];
  #pragma unroll
  for (int t = 0; t < 8; ++t) a[t] = bj;
  for (int f = 0; f < 16; ++f) {
    float wv = W1[f * 64 + j];
    #pragma unroll
    for (int t = 0; t < 8; ++t) a[t] = fmaf(xs[nb * 128 + f * 8 + t], wv, a[t]);
  }
  #pragma unroll
  for (int t = 0; t < 8; ++t) h1s[nb][t][j] = fmaxf(a[t], 0.f);
  __syncthreads();
  float g[8];
  #pragma unroll
  for (int t = 0; t < 8; ++t) g[t] = 0.f;
  for (int k = 0; k < 64; ++k) {
    float wv = W2[k * 64 + j];
    #pragma unroll
    for (int t = 0; t < 8; ++t) g[t] = fmaf(h1s[nb][t][k], wv, g[t]);
  }
  __half* gp = G2h + (size_t)(n0 + nb) * 512 + j;
  #pragma unroll
  for (int t = 0; t < 8; ++t) gp[t * 64] = __float2half_rn(g[t]);
}

// ---------------- conv2: aggregate G2h (1KB fp16 rows, 4-deep); h2=relu(+b2); G3h = h2 @ W3 ----------------
__global__ void conv2w_kernel(const __half* __restrict__ G2h, const float* __restrict__ dinv,
                              const int* __restrict__ rowptr, const int* __restrict__ csr_src,
                              const float* __restrict__ csr_norm, const float* __restrict__ b2,
                              const float* __restrict__ W3, __half* __restrict__ G3h) {
  __shared__ float h2s[4][512];
  int tid = threadIdx.x;
  int w = tid >> 6, l = tid & 63;
  int n0 = blockIdx.x * 4;
  int n = n0 + w;
  float di = dinv[n], dd = di * di;
  int e0 = rowptr[n], e1 = rowptr[n + 1];
  int cnt = e1 - e0 + 1;             // item 0 = self
  float acc[8] = {0, 0, 0, 0, 0, 0, 0, 0};
  int sm[4]; float wm[4];
  #pragma unroll
  for (int q = 0; q < 4; ++q) {
    int idx = q;
    if (idx == 0)       { sm[q] = n; wm[q] = dd; }
    else if (idx < cnt) { int e = e0 + idx - 1; sm[q] = csr_src[e]; wm[q] = csr_norm[e]; }
    else                { sm[q] = n; wm[q] = 0.f; }
  }
  for (int i = 0; i < cnt; i += 4) {
    uint4 r0 = *reinterpret_cast<const uint4*>(G2h + (size_t)sm[0] * 512 + l * 8);
    uint4 r1 = *reinterpret_cast<const uint4*>(G2h + (size_t)sm[1] * 512 + l * 8);
    uint4 r2 = *reinterpret_cast<const uint4*>(G2h + (size_t)sm[2] * 512 + l * 8);
    uint4 r3 = *reinterpret_cast<const uint4*>(G2h + (size_t)sm[3] * 512 + l * 8);
    float w0 = wm[0], w1 = wm[1], w2 = wm[2], w3 = wm[3];
    #pragma unroll
    for (int q = 0; q < 4; ++q) {
      int idx = i + 4 + q;           // >= 4, never self
      if (idx < cnt) { int e = e0 + idx - 1; sm[q] = csr_src[e]; wm[q] = csr_norm[e]; }
      else           { sm[q] = n; wm[q] = 0.f; }
    }
    accum8(acc, r0, w0);
    accum8(acc, r1, w1);
    accum8(acc, r2, w2);
    accum8(acc, r3, w3);
  }
  #pragma unroll
  for (int q = 0; q < 8; ++q)
    h2s[w][l * 8 + q] = fmaxf(acc[q] + b2[(l * 8 + q) & 63], 0.f);
  __syncthreads();
  // per-t dense: G3[t*64 + j] = sum_k h2[t*64+k] * W3[k][j]
  int t = tid >> 5;            // 0..7
  int jh = tid & 31, j0 = 2 * jh;
  float g[4][2];
  #pragma unroll
  for (int q = 0; q < 4; ++q) { g[q][0] = 0.f; g[q][1] = 0.f; }
  const float2* W3v = (const float2*)W3;
  for (int k = 0; k < 64; ++k) {
    float2 wv = W3v[k * 32 + jh];
    #pragma unroll
    for (int q = 0; q < 4; ++q) {
      float h = h2s[q][t * 64 + k];
      g[q][0] = fmaf(h, wv.x, g[q][0]);
      g[q][1] = fmaf(h, wv.y, g[q][1]);
    }
  }
  #pragma unroll
  for (int q = 0; q < 4; ++q) {
    __half2 hv;
    hv.x = __float2half_rn(g[q][0]);
    hv.y = __float2half_rn(g[q][1]);
    *reinterpret_cast<__half2*>(G3h + (size_t)(n0 + q) * 512 + t * 64 + j0) = hv;
  }
}

// ---------------- conv3 + head: aggregate G3h (4-deep); h3=relu(+b3); out = relu(h3@Wseq+bseq)@Wcls+bcls ----------------
__global__ void conv3w_kernel(const __half* __restrict__ G3h, const float* __restrict__ dinv,
                              const int* __restrict__ rowptr, const int* __restrict__ csr_src,
                              const float* __restrict__ csr_norm, const float* __restrict__ b3,
                              const float* __restrict__ Wseq, const float* __restrict__ bseq,
                              const float* __restrict__ Wcls, const float* __restrict__ bcls,
                              float* __restrict__ out) {
  __shared__ float h3s[4][512];
  __shared__ float red[4][4][64];
  __shared__ float hfs[4][64];
  int tid = threadIdx.x;
  int w = tid >> 6, l = tid & 63;
  int n0 = blockIdx.x * 4;
  int n = n0 + w;
  float di = dinv[n], dd = di * di;
  int e0 = rowptr[n], e1 = rowptr[n + 1];
  int cnt = e1 - e0 + 1;
  float acc[8] = {0, 0, 0, 0, 0, 0, 0, 0};
  int sm[4]; float wm[4];
  #pragma unroll
  for (int q = 0; q < 4; ++q) {
    int idx = q;
    if (idx == 0)       { sm[q] = n; wm[q] = dd; }
    else if (idx < cnt) { int e = e0 + idx - 1; sm[q] = csr_src[e]; wm[q] = csr_norm[e]; }
    else                { sm[q] = n; wm[q] = 0.f; }
  }
  for (int i = 0; i < cnt; i += 4) {
    uint4 r0 = *reinterpret_cast<const uint4*>(G3h + (size_t)sm[0] * 512 + l * 8);
    uint4 r1 = *reinterpret_cast<const uint4*>(G3h + (size_t)sm[1] * 512 + l * 8);
    uint4 r2 = *reinterpret_cast<const uint4*>(G3h + (size_t)sm[2] * 512 + l * 8);
    uint4 r3 = *reinterpret_cast<const uint4*>(G3h + (size_t)sm[3] * 512 + l * 8);
    float w0 = wm[0], w1 = wm[1], w2 = wm[2], w3 = wm[3];
    #pragma unroll
    for (int q = 0; q < 4; ++q) {
      int idx = i + 4 + q;
      if (idx < cnt) { int e = e0 + idx - 1; sm[q] = csr_src[e]; wm[q] = csr_norm[e]; }
      else           { sm[q] = n; wm[q] = 0.f; }
    }
    accum8(acc, r0, w0);
    accum8(acc, r1, w1);
    accum8(acc, r2, w2);
    accum8(acc, r3, w3);
  }
  #pragma unroll
  for (int q = 0; q < 8; ++q)
    h3s[w][l * 8 + q] = fmaxf(acc[q] + b3[(l * 8 + q) & 63], 0.f);
  __syncthreads();
  // seq contraction: partial[p][nb][j] = sum_{c in p-range} h3[nb][c] * Wseq[c][j]
  int p = tid >> 6, j = tid & 63;
  float pa0 = 0.f, pa1 = 0.f, pa2 = 0.f, pa3 = 0.f;
  for (int ci = 0; ci < 128; ++ci) {
    int c = p * 128 + ci;
    float wv = Wseq[(size_t)c * 64 + j];
    pa0 = fmaf(h3s[0][c], wv, pa0);
    pa1 = fmaf(h3s[1][c], wv, pa1);
    pa2 = fmaf(h3s[2][c], wv, pa2);
    pa3 = fmaf(h3s[3][c], wv, pa3);
  }
  red[p][0][j] = pa0; red[p][1][j] = pa1; red[p][2][j] = pa2; red[p][3][j] = pa3;
  __syncthreads();
  int nb = tid >> 6, k = tid & 63;
  float s = red[0][nb][k] + red[1][nb][k] + red[2][nb][k] + red[3][nb][k] + bseq[k];
  hfs[nb][k] = fmaxf(s, 0.f);
  __syncthreads();
  if (k < C) {
    float o = bcls[k];
    #pragma unroll
    for (int kk = 0; kk < 64; ++kk) o = fmaf(hfs[nb][kk], Wcls[kk * C + k], o);
    out[(size_t)(n0 + nb) * C + k] = o;
  }
}

// ================= NARROW FALLBACK (fp32, per-t) =================
__global__ void layer1N_kernel(const float* __restrict__ xagg, const float* __restrict__ W1,
                               const float* __restrict__ b1, const float* __restrict__ W2,
                               float* __restrict__ GA, int t) {
  __shared__ float hs[4][H];
  int tid = threadIdx.x;
  int wv = tid >> 6, j = tid & 63;
  int n = blockIdx.x * 4 + wv;
  const float* xa = xagg + (size_t)n * 128;
  float a = b1[j];
  #pragma unroll
  for (int f = 0; f < 16; ++f) a += xa[f * 8 + t] * W1[f * H + j];
  hs[wv][j] = fmaxf(a, 0.f);
  __syncthreads();
  float g = 0.f;
  #pragma unroll
  for (int k = 0; k < H; ++k) g += hs[wv][k] * W2[k * H + j];
  GA[(size_t)n * H + j] = g;
}

template<bool ACCUM>
__global__ void convN_kernel(const float* __restrict__ Gin, const float* __restrict__ dinv,
                             const int* __restrict__ rowptr, const int* __restrict__ csr_src,
                             const float* __restrict__ csr_norm, const float* __restrict__ b,
                             const float* __restrict__ Wnext, float* __restrict__ Gout) {
  __shared__ __align__(16) float hs[4][H];
  int tid = threadIdx.x;
  int wv = tid >> 6, lane = tid & 63;
  int sub = lane >> 4, q = lane & 15;
  int n = blockIdx.x * 4 + wv;
  float di = dinv[n];
  const float4* G4 = (const float4*)Gin;
  float4 a0 = {0,0,0,0}, a1 = {0,0,0,0};
  int e0 = rowptr[n], e1 = rowptr[n + 1];
  int e = e0 + sub;
  for (; e + 4 < e1; e += 8) {
    int s0 = csr_src[e];     float w0 = csr_norm[e];
    int s1 = csr_src[e + 4]; float w1 = csr_norm[e + 4];
    float4 r0 = G4[(size_t)s0 * 16 + q];
    float4 r1 = G4[(size_t)s1 * 16 + q];
    a0.x += w0 * r0.x; a0.y += w0 * r0.y; a0.z += w0 * r0.z; a0.w += w0 * r0.w;
    a1.x += w1 * r1.x; a1.y += w1 * r1.y; a1.z += w1 * r1.z; a1.w += w1 * r1.w;
  }
  for (; e < e1; e += 4) {
    int s0 = csr_src[e]; float w0 = csr_norm[e];
    float4 r0 = G4[(size_t)s0 * 16 + q];
    a0.x += w0 * r0.x; a0.y += w0 * r0.y; a0.z += w0 * r0.z; a0.w += w0 * r0.w;
  }
  a0.x += a1.x; a0.y += a1.y; a0.z += a1.z; a0.w += a1.w;
  #pragma unroll
  for (int off = 16; off <= 32; off <<= 1) {
    a0.x += __shfl_xor(a0.x, off, 64);
    a0.y += __shfl_xor(a0.y, off, 64);
    a0.z += __shfl_xor(a0.z, off, 64);
    a0.w += __shfl_xor(a0.w, off, 64);
  }
  float4 own = G4[(size_t)n * 16 + q];
  float dd = di * di;
  if (sub == 0) {
    float4 h;
    h.x = fmaxf(a0.x + dd * own.x + b[4 * q + 0], 0.f);
    h.y = fmaxf(a0.y + dd * own.y + b[4 * q + 1], 0.f);
    h.z = fmaxf(a0.z + dd * own.z + b[4 * q + 2], 0.f);
    h.w = fmaxf(a0.w + dd * own.w + b[4 * q + 3], 0.f);
    ((float4*)hs[wv])[q] = h;
  }
  __syncthreads();
  float g = 0.f;
  #pragma unroll
  for (int k = 0; k < H; ++k) g += hs[wv][k] * Wnext[k * H + lane];
  if (ACCUM) Gout[(size_t)n * H + lane] += g;
  else       Gout[(size_t)n * H + lane]  = g;
}

__global__ void final_kernel(const float* __restrict__ acc, const float* __restrict__ bseq,
                             const float* __restrict__ Wcls, const float* __restrict__ bcls,
                             float* __restrict__ out) {
  __shared__ float hs[4][H];
  int tid = threadIdx.x;
  int wv = tid >> 6, j = tid & 63;
  int n = blockIdx.x * 4 + wv;
  hs[wv][j] = fmaxf(acc[(size_t)n * H + j] + bseq[j], 0.0f);
  __syncthreads();
  if (j < C) {
    float o = bcls[j];
    #pragma unroll
    for (int k = 0; k < H; ++k) o += hs[wv][k] * Wcls[k * C + j];
    out[(size_t)n * C + j] = o;
  }
}

extern "C" void kernel_launch(void* const* d_in, const int* in_sizes, int n_in,
                              void* d_out, int out_size, void* d_ws, size_t ws_size,
                              hipStream_t stream) {
  const float* x    = (const float*)d_in[0];
  const int*   ei   = (const int*)  d_in[1];
  const float* w    = (const float*)d_in[2];
  const float* W1   = (const float*)d_in[3];
  const float* b1   = (const float*)d_in[4];
  const float* W2   = (const float*)d_in[5];
  const float* b2   = (const float*)d_in[6];
  const float* W3   = (const float*)d_in[7];
  const float* b3   = (const float*)d_in[8];
  const float* Wseq = (const float*)d_in[9];
  const float* bseq = (const float*)d_in[10];
  const float* Wcls = (const float*)d_in[11];
  const float* bcls = (const float*)d_in[12];
  float* out = (float*)d_out;

  char* p = (char*)d_ws;
  auto alloc = [&](size_t bytes) -> char* {
    char* r = p; p += (bytes + 255) & ~(size_t)255; return r;
  };
  float*  deg     = (float*) alloc((size_t)N * 4);      // becomes dinv
  int*    counts  = (int*)   alloc((size_t)N * 4);
  int*    fillc   = (int*)   alloc((size_t)N * 4);
  int*    rowptr  = (int*)   alloc((size_t)(N + 1) * 4);
  int*    bsum    = (int*)   alloc(64 * 4);
  int*    boff    = (int*)   alloc(64 * 4);
  int*    csr_src = (int*)   alloc((size_t)E * 4);
  float*  csr_nrm = (float*) alloc((size_t)E * 4);
  float*  xagg    = (float*) alloc((size_t)N * 128 * 4);
  __half* xh      = (__half*)alloc((size_t)N * 128 * 2);

  hipMemsetAsync(deg,    0, (size_t)N * 4, stream);
  hipMemsetAsync(counts, 0, (size_t)N * 4, stream);
  hipMemsetAsync(fillc,  0, (size_t)N * 4, stream);

  constexpr int NTILES = (N + 1023) / 1024;   // 49
  cvt_x_kernel<<<(N * 32 + 255) / 256, 256, 0, stream>>>(x, xh);
  deg_count_kernel<<<(E + 255) / 256, 256, 0, stream>>>(ei, w, deg, counts);
  dinv_kernel<<<(N + 255) / 256, 256, 0, stream>>>(deg);
  scanA_kernel<<<NTILES, 256, 0, stream>>>(counts, rowptr, bsum);
  scanB_kernel<<<1, 64, 0, stream>>>(bsum, boff, NTILES);
  scanC_kernel<<<(N + 255) / 256, 256, 0, stream>>>(rowptr, boff);
  fill_kernel<<<(E + 255) / 256, 256, 0, stream>>>(ei, w, deg, rowptr, fillc, csr_src, csr_nrm);
  agg_x_kernel<<<N / 4, 256, 0, stream>>>(xh, deg, rowptr, csr_src, csr_nrm, xagg);

  // wide needs: common ~52MB + G2h 51.2MB + G3h 51.2MB ~= 155MB
  bool wide = ws_size >= (size_t)155 * 1000 * 1000;

  if (wide) {
    __half* G2h = (__half*)alloc((size_t)N * 512 * 2);
    __half* G3h = (__half*)alloc((size_t)N * 512 * 2);
    dense12_kernel<<<N / 4, 256, 0, stream>>>(xagg, W1, b1, W2, G2h);
    conv2w_kernel<<<N / 4, 256, 0, stream>>>(G2h, deg, rowptr, csr_src, csr_nrm, b2, W3, G3h);
    conv3w_kernel<<<N / 4, 256, 0, stream>>>(G3h, deg, rowptr, csr_src, csr_nrm, b3,
                                             Wseq, bseq, Wcls, bcls, out);
  } else {
    float* GA  = (float*)alloc((size_t)N * H * 4);
    float* GB  = (float*)alloc((size_t)N * H * 4);
    float* acc = (float*)alloc((size_t)N * H * 4);
    hipMemsetAsync(acc, 0, (size_t)N * H * 4, stream);
    for (int t = 0; t < T; ++t) {
      layer1N_kernel<<<N / 4, 256, 0, stream>>>(xagg, W1, b1, W2, GA, t);
      convN_kernel<false><<<N / 4, 256, 0, stream>>>(GA, deg, rowptr, csr_src, csr_nrm, b2, W3, GB);
      convN_kernel<true ><<<N / 4, 256, 0, stream>>>(GB, deg, rowptr, csr_src, csr_nrm, b3,
                                                     Wseq + (size_t)t * H * H, acc);
    }
    final_kernel<<<N / 4, 256, 0, stream>>>(acc, bseq, Wcls, bcls, out);
  }
}